// Round 1
// baseline (142.564 us; speedup 1.0000x reference)
//
#include <hip/hip_runtime.h>
#include <hip/hip_bf16.h>

#define B_  128
#define T_  512
#define N1_ 512
#define K_  8
#define CAPf 50.0f
#define NEG_INF_F (-1000000000.0f)

// ---------------------------------------------------------------------------
// Kernel 1: per-batch prep.
//  - first_visit[b][n] = min t with actions[b,t]==n (else INT_MAX)   [vis mask]
//  - used[b][t] = capacity-used state BEFORE step t (bit-exact serial scan,
//    reference order: u_{t+1} = (a_t==0) ? 0 : u_t + demands[b,a_t])
//  - c[b][n] = lambda * interf[b][n] = lambda * sum_k psi[b,n]·psi[b,knn[b,n,k]]
// ---------------------------------------------------------------------------
__global__ __launch_bounds__(256) void prep_kernel(
    const float* __restrict__ psi,       // (B,N1,2)
    const float* __restrict__ demands,   // (B,N1)
    const float* __restrict__ lambda_p,  // (1)
    const int*   __restrict__ actions,   // (B,T)
    const int*   __restrict__ knn,       // (B,N1,K)
    float* __restrict__ ws_used,         // (B,T)
    int*   __restrict__ ws_fv,           // (B,N1)
    float* __restrict__ ws_c)            // (B,N1)
{
    __shared__ int   act_l[T_];
    __shared__ float d_l[T_];
    __shared__ float used_l[T_];
    __shared__ int   fv_l[N1_];

    const int b   = blockIdx.x;
    const int tid = threadIdx.x;

    for (int t = tid; t < T_;  t += 256) act_l[t] = actions[b * T_ + t];
    for (int n = tid; n < N1_; n += 256) fv_l[n]  = 0x7fffffff;
    __syncthreads();

    for (int t = tid; t < T_; t += 256) {
        int a = act_l[t];
        atomicMin(&fv_l[a], t);
        d_l[t] = demands[b * N1_ + a];   // gather (L1/L2 resident row)
    }
    __syncthreads();

    if (tid == 0) {
        // Strictly sequential, identical op order to the jax scan -> bit-exact.
        float u = 0.0f;
        for (int t = 0; t < T_; ++t) {
            used_l[t] = u;
            u = (act_l[t] == 0) ? 0.0f : (u + d_l[t]);
        }
    }
    __syncthreads();

    for (int t = tid; t < T_;  t += 256) ws_used[b * T_ + t] = used_l[t];
    for (int n = tid; n < N1_; n += 256) ws_fv[b * N1_ + n]  = fv_l[n];

    const float lam = *lambda_p;
    const float2* psi2 = (const float2*)psi;
    for (int n = tid; n < N1_; n += 256) {
        float2 p = psi2[b * N1_ + n];
        const int4* kk = (const int4*)(knn + ((size_t)b * N1_ + n) * K_);
        int4 k0 = kk[0], k1 = kk[1];
        int ks[8] = {k0.x, k0.y, k0.z, k0.w, k1.x, k1.y, k1.z, k1.w};
        float acc = 0.0f;
        #pragma unroll
        for (int k = 0; k < 8; ++k) {
            float2 q = psi2[b * N1_ + ks[k]];
            acc += p.x * q.x + p.y * q.y;
        }
        ws_c[b * N1_ + n] = lam * acc;
    }
}

// ---------------------------------------------------------------------------
// Kernel 2: per-(b,t) row: scores -> mask -> log_softmax -> lp_new, entropy.
// One wave per row; 8 n-elements per lane. Block = 4 waves x 8 rows = 32 t's.
// ---------------------------------------------------------------------------
__global__ __launch_bounds__(256) void main_kernel(
    const float* __restrict__ psi,      // (B,N1,2)
    const float* __restrict__ demands,  // (B,N1)
    const float* __restrict__ Wq_w,     // (2,4)
    const float* __restrict__ Wq_b,     // (2)
    const int*   __restrict__ actions,  // (B,T)
    const float* __restrict__ ws_used,  // (B,T)
    const int*   __restrict__ ws_fv,    // (B,N1)
    const float* __restrict__ ws_c,     // (B,N1)
    float* __restrict__ out_lp,         // (B,T)
    float* __restrict__ out_ent)        // (B)
{
    __shared__ float2 psi_l[N1_];
    __shared__ float  c_l[N1_];
    __shared__ float  dem_l[N1_];
    __shared__ int    fv_l[N1_];
    __shared__ float  ent_sh;

    const int bid    = blockIdx.x;
    const int b      = bid >> 4;       // 16 chunks of 32 t's
    const int t_base = (bid & 15) * 32;
    const int tid    = threadIdx.x;
    const int wave   = tid >> 6;
    const int lane   = tid & 63;

    if (tid == 0) ent_sh = 0.0f;

    const float2* psi2 = (const float2*)psi;
    for (int i = tid; i < N1_; i += 256) {
        psi_l[i] = psi2[b * N1_ + i];
        c_l[i]   = ws_c[b * N1_ + i];
        dem_l[i] = demands[b * N1_ + i];
        fv_l[i]  = ws_fv[b * N1_ + i];
    }

    const float W00 = Wq_w[0], W01 = Wq_w[1], W02 = Wq_w[2], W03 = Wq_w[3];
    const float W10 = Wq_w[4], W11 = Wq_w[5], W12 = Wq_w[6], W13 = Wq_w[7];
    const float bq0 = Wq_b[0], bq1 = Wq_b[1];
    __syncthreads();

    float ent_acc = 0.0f;

    #pragma unroll 1
    for (int r = 0; r < 8; ++r) {
        const int t = t_base + wave * 8 + r;

        const int   cur  = (t == 0) ? 0 : actions[b * T_ + t - 1];
        const int   a    = actions[b * T_ + t];
        const float used = ws_used[b * T_ + t];
        const float rem  = CAPf - used;
        const float cap  = rem / CAPf;
        const float tn   = (float)t / 511.0f;
        const bool  at_depot = (cur == 0);

        float pcx = 0.0f, pcy = 0.0f;
        if (!at_depot) { float2 pc = psi_l[cur]; pcx = pc.x; pcy = pc.y; }

        const float q0 = pcx * W00 + pcy * W01 + cap * W02 + tn * W03 + bq0;
        const float q1 = pcx * W10 + pcy * W11 + cap * W12 + tn * W13 + bq1;

        float s[8];
        bool avail = false;
        #pragma unroll
        for (int j = 0; j < 8; ++j) {
            const int n = j * 64 + lane;
            float2 p = psi_l[n];
            float sc = q0 * p.x + q1 * p.y + c_l[n];
            if (n != 0) {   // customers: vis | exceeds mask
                bool m = (fv_l[n] < t) | (dem_l[n] > rem);
                avail |= !m;
                if (m) sc = NEG_INF_F;
            }
            s[j] = sc;
        }

        const bool has_cust = __any((int)avail);
        if (lane == 0 && at_depot && has_cust) s[0] = NEG_INF_F;

        // row max
        float mx = s[0];
        #pragma unroll
        for (int j = 1; j < 8; ++j) mx = fmaxf(mx, s[j]);
        #pragma unroll
        for (int off = 32; off > 0; off >>= 1)
            mx = fmaxf(mx, __shfl_xor(mx, off, 64));

        // S1 = sum exp(s-mx), S2 = sum exp(s-mx)*s  (masked terms underflow to 0)
        float S1 = 0.0f, S2 = 0.0f;
        #pragma unroll
        for (int j = 0; j < 8; ++j) {
            float e = expf(s[j] - mx);
            S1 += e;
            S2 += e * s[j];
        }
        #pragma unroll
        for (int off = 32; off > 0; off >>= 1) {
            S1 += __shfl_xor(S1, off, 64);
            S2 += __shfl_xor(S2, off, 64);
        }
        const float lse = mx + logf(S1);

        // score at taken action (post-mask value)
        float sa = 0.0f;
        #pragma unroll
        for (int j = 0; j < 8; ++j) { if (j * 64 + lane == a) sa = s[j]; }
        const float s_a = __shfl(sa, a & 63, 64);

        if (lane == 0) out_lp[b * T_ + t] = s_a - lse;
        ent_acc += (lse - S2 / S1);
    }

    if (lane == 0) atomicAdd(&ent_sh, ent_acc);
    __syncthreads();
    if (tid == 0) atomicAdd(&out_ent[b], ent_sh * (1.0f / 512.0f));
}

// ---------------------------------------------------------------------------
extern "C" void kernel_launch(void* const* d_in, const int* in_sizes, int n_in,
                              void* d_out, int out_size, void* d_ws, size_t ws_size,
                              hipStream_t stream) {
    const float* psi      = (const float*)d_in[0];
    const float* demands  = (const float*)d_in[1];
    const float* Wq_w     = (const float*)d_in[2];
    const float* Wq_b     = (const float*)d_in[3];
    const float* lam      = (const float*)d_in[4];
    const int*   actions  = (const int*)d_in[5];
    const int*   knn      = (const int*)d_in[6];

    float* out_lp  = (float*)d_out;                 // (B,T)
    float* out_ent = out_lp + (size_t)B_ * T_;      // (B)

    float* ws_used = (float*)d_ws;                                          // B*T f32
    int*   ws_fv   = (int*)  ((char*)d_ws + (size_t)B_ * T_ * 4);           // B*N1 i32
    float* ws_c    = (float*)((char*)d_ws + (size_t)B_ * T_ * 4
                                          + (size_t)B_ * N1_ * 4);          // B*N1 f32

    hipMemsetAsync(out_ent, 0, B_ * sizeof(float), stream);

    prep_kernel<<<B_, 256, 0, stream>>>(psi, demands, lam, actions, knn,
                                        ws_used, ws_fv, ws_c);
    main_kernel<<<B_ * 16, 256, 0, stream>>>(psi, demands, Wq_w, Wq_b, actions,
                                             ws_used, ws_fv, ws_c,
                                             out_lp, out_ent);
}

// Round 5
// 107.299 us; speedup vs baseline: 1.3287x; 1.3287x over previous
//
#include <hip/hip_runtime.h>
#include <hip/hip_bf16.h>

#define B_  128
#define T_  512
#define N1_ 512
#define K_  8
#define CAPf 50.0f
#define NEG_INF_F (-1000000000.0f)

// ---------------------------------------------------------------------------
// Kernel 1: per-batch prep.
//  - first_visit[b][n] = min t with actions[b,t]==n (else INT_MAX)
//  - used[b][t]: bit-exact serial scan via u = fma(m,u,dv); m=0 resets exactly,
//    m=1 gives round(u+d) == reference's f32 add. (m,dv) prepacked in LDS so
//    the unrolled loop pipelines ds_read_b64 ahead of the 4-cyc fma chain.
//  - c[b][n] = lambda * interf, computed on threads 64..255 WHILE lane 0 scans.
// ---------------------------------------------------------------------------
__global__ __launch_bounds__(256) void prep_kernel(
    const float* __restrict__ psi,       // (B,N1,2)
    const float* __restrict__ demands,   // (B,N1)
    const float* __restrict__ lambda_p,  // (1)
    const int*   __restrict__ actions,   // (B,T)
    const int*   __restrict__ knn,       // (B,N1,K)
    float* __restrict__ ws_used,         // (B,T)
    int*   __restrict__ ws_fv,           // (B,N1)
    float* __restrict__ ws_c)            // (B,N1)
{
    __shared__ int    act_l[T_];
    __shared__ float2 md_l[T_];     // (mult, add) per step for the fma scan
    __shared__ float  used_l[T_];
    __shared__ int    fv_l[N1_];

    const int b   = blockIdx.x;
    const int tid = threadIdx.x;

    for (int t = tid; t < T_;  t += 256) act_l[t] = actions[b * T_ + t];
    for (int n = tid; n < N1_; n += 256) fv_l[n]  = 0x7fffffff;
    __syncthreads();

    for (int t = tid; t < T_; t += 256) {
        int a = act_l[t];
        atomicMin(&fv_l[a], t);
        float d = demands[b * N1_ + a];
        md_l[t] = (a == 0) ? make_float2(0.0f, 0.0f) : make_float2(1.0f, d);
    }
    __syncthreads();

    if (tid == 0) {
        // Bit-exact vs reference: fma(1,u,d) rounds once == fl(u+d); fma(0,u,0)==0.
        float u = 0.0f;
        #pragma unroll 8
        for (int t = 0; t < T_; ++t) {
            used_l[t] = u;
            float2 md = md_l[t];
            u = fmaf(md.x, u, md.y);
        }
    } else if (tid >= 64) {
        // interf on 192 threads, overlapped with the scan
        const float lam = *lambda_p;
        const float2* psi2 = (const float2*)psi;
        for (int n = tid - 64; n < N1_; n += 192) {
            float2 p = psi2[b * N1_ + n];
            const int4* kk = (const int4*)(knn + ((size_t)b * N1_ + n) * K_);
            int4 k0 = kk[0], k1 = kk[1];
            int ks[8] = {k0.x, k0.y, k0.z, k0.w, k1.x, k1.y, k1.z, k1.w};
            float acc = 0.0f;
            #pragma unroll
            for (int k = 0; k < 8; ++k) {
                float2 q = psi2[b * N1_ + ks[k]];
                acc = fmaf(p.x, q.x, acc);
                acc = fmaf(p.y, q.y, acc);
            }
            ws_c[b * N1_ + n] = lam * acc;
        }
    }
    __syncthreads();

    for (int t = tid; t < T_;  t += 256) ws_used[b * T_ + t] = used_l[t];
    for (int n = tid; n < N1_; n += 256) ws_fv[b * N1_ + n]  = fv_l[n];
}

// ---------------------------------------------------------------------------
// Kernel 2: per-(b,t) row: scores -> mask -> log_softmax -> lp_new, entropy.
// One wave per row; 8 n-elements per lane; packed float4{px,py,c,dem} in LDS
// so the hot loop does 1x ds_read_b128 + 1x ds_read_b32 per element.
// ---------------------------------------------------------------------------
__global__ __launch_bounds__(256) void main_kernel(
    const float* __restrict__ psi,      // (B,N1,2)
    const float* __restrict__ demands,  // (B,N1)
    const float* __restrict__ Wq_w,     // (2,4)
    const float* __restrict__ Wq_b,     // (2)
    const int*   __restrict__ actions,  // (B,T)
    const float* __restrict__ ws_used,  // (B,T)
    const int*   __restrict__ ws_fv,    // (B,N1)
    const float* __restrict__ ws_c,     // (B,N1)
    float* __restrict__ out_lp,         // (B,T)
    float* __restrict__ out_ent)        // (B)
{
    __shared__ float4 pk_l[N1_];        // {psi.x, psi.y, lam*interf, demand}
    __shared__ int    fv_l[N1_];
    __shared__ float  ent_sh;

    const int bid    = blockIdx.x;
    const int b      = bid >> 4;        // 16 chunks of 32 t's per batch
    const int t_base = (bid & 15) * 32;
    const int tid    = threadIdx.x;
    const int wave   = tid >> 6;
    const int lane   = tid & 63;

    if (tid == 0) ent_sh = 0.0f;

    const float2* psi2 = (const float2*)psi;
    for (int i = tid; i < N1_; i += 256) {
        float2 p = psi2[b * N1_ + i];
        pk_l[i] = make_float4(p.x, p.y, ws_c[b * N1_ + i], demands[b * N1_ + i]);
        fv_l[i] = ws_fv[b * N1_ + i];
    }

    const float W00 = Wq_w[0], W01 = Wq_w[1], W02 = Wq_w[2], W03 = Wq_w[3];
    const float W10 = Wq_w[4], W11 = Wq_w[5], W12 = Wq_w[6], W13 = Wq_w[7];
    const float bq0 = Wq_b[0], bq1 = Wq_b[1];
    __syncthreads();

    float ent_acc = 0.0f;

    #pragma unroll 1
    for (int r = 0; r < 8; ++r) {
        const int t = t_base + wave * 8 + r;

        const int   cur  = (t == 0) ? 0 : actions[b * T_ + t - 1];
        const int   a    = actions[b * T_ + t];
        const float rem  = CAPf - ws_used[b * T_ + t];
        const float cap  = rem * (1.0f / CAPf);
        const float tn   = (float)t * (1.0f / 511.0f);
        const bool  at_depot = (cur == 0);

        float pcx = 0.0f, pcy = 0.0f;
        if (!at_depot) { float4 pc = pk_l[cur]; pcx = pc.x; pcy = pc.y; }

        const float q0 = fmaf(pcx, W00, fmaf(pcy, W01, fmaf(cap, W02, fmaf(tn, W03, bq0))));
        const float q1 = fmaf(pcx, W10, fmaf(pcy, W11, fmaf(cap, W12, fmaf(tn, W13, bq1))));

        float s[8];
        bool avail = false;
        #pragma unroll
        for (int j = 0; j < 8; ++j) {
            const int n = j * 64 + lane;
            float4 P = pk_l[n];
            float sc = fmaf(q0, P.x, fmaf(q1, P.y, P.z));
            if (n != 0) {   // customers: vis | exceeds mask
                bool m = (fv_l[n] < t) | (P.w > rem);
                avail |= !m;
                sc = m ? NEG_INF_F : sc;
            }
            s[j] = sc;
        }

        const bool has_cust = __any((int)avail);
        if (lane == 0 && at_depot && has_cust) s[0] = NEG_INF_F;

        // row max (always >= one finite score: depot unmasks when no customer)
        float mx = s[0];
        #pragma unroll
        for (int j = 1; j < 8; ++j) mx = fmaxf(mx, s[j]);
        #pragma unroll
        for (int off = 32; off > 0; off >>= 1)
            mx = fmaxf(mx, __shfl_xor(mx, off, 64));

        // S1 = sum exp(s-mx); S2 = sum exp(s-mx)*s. Masked: exp underflows to 0.
        float S1 = 0.0f, S2 = 0.0f;
        #pragma unroll
        for (int j = 0; j < 8; ++j) {
            float e = __expf(s[j] - mx);
            S1 += e;
            S2 = fmaf(e, s[j], S2);
        }
        #pragma unroll
        for (int off = 32; off > 0; off >>= 1) {
            S1 += __shfl_xor(S1, off, 64);
            S2 += __shfl_xor(S2, off, 64);
        }
        const float lse = mx + __logf(S1);

        // score at taken action (post-mask value)
        float sa = 0.0f;
        #pragma unroll
        for (int j = 0; j < 8; ++j) { if (j * 64 + lane == a) sa = s[j]; }
        const float s_a = __shfl(sa, a & 63, 64);

        if (lane == 0) out_lp[b * T_ + t] = s_a - lse;
        ent_acc += lse - __fdividef(S2, S1);
    }

    if (lane == 0) atomicAdd(&ent_sh, ent_acc);
    __syncthreads();
    if (tid == 0) atomicAdd(&out_ent[b], ent_sh * (1.0f / 512.0f));
}

// ---------------------------------------------------------------------------
extern "C" void kernel_launch(void* const* d_in, const int* in_sizes, int n_in,
                              void* d_out, int out_size, void* d_ws, size_t ws_size,
                              hipStream_t stream) {
    const float* psi      = (const float*)d_in[0];
    const float* demands  = (const float*)d_in[1];
    const float* Wq_w     = (const float*)d_in[2];
    const float* Wq_b     = (const float*)d_in[3];
    const float* lam      = (const float*)d_in[4];
    const int*   actions  = (const int*)d_in[5];
    const int*   knn      = (const int*)d_in[6];

    float* out_lp  = (float*)d_out;                 // (B,T)
    float* out_ent = out_lp + (size_t)B_ * T_;      // (B)

    float* ws_used = (float*)d_ws;                                          // B*T f32
    int*   ws_fv   = (int*)  ((char*)d_ws + (size_t)B_ * T_ * 4);           // B*N1 i32
    float* ws_c    = (float*)((char*)d_ws + (size_t)B_ * T_ * 4
                                          + (size_t)B_ * N1_ * 4);          // B*N1 f32

    hipMemsetAsync(out_ent, 0, B_ * sizeof(float), stream);

    prep_kernel<<<B_, 256, 0, stream>>>(psi, demands, lam, actions, knn,
                                        ws_used, ws_fv, ws_c);
    main_kernel<<<B_ * 16, 256, 0, stream>>>(psi, demands, Wq_w, Wq_b, actions,
                                             ws_used, ws_fv, ws_c,
                                             out_lp, out_ent);
}